// Round 11
// baseline (193.659 us; speedup 1.0000x reference)
//
#include <hip/hip_runtime.h>
#include <hip/hip_fp16.h>

#define IN_DIM   128
#define OUT_DIM  128
#define ATTN_DIM 64
#define N_RELV   401
#define N_NODE   50000
#define N_EDGE   500000
#define N_QUERY  64
#define N_DT     731
#define CAP      40       // padded bucket capacity (deg ~ Poisson(10); P(>=40) ~ 1e-11)

// fused_pre block roles (256 threads/block; node blocks cover 64 rows)
#define NBW_NODE 782              // ceil(50000/64)
#define NBW_REL  7                // 7*64 = 448 >= 401
#define NBW_DT   12               // 12*64 = 768 >= 731
#define NBW_QR   1                // 64 queries
#define NBW_ZERO 13               // cnt zeroing
#define RB0      NBW_NODE
#define DB0      (NBW_NODE + NBW_REL)
#define QB0      (DB0 + NBW_DT)
#define ZB0      (QB0 + NBW_QR)
#define FB0      (ZB0 + NBW_ZERO)
#define NB_TOT   (FB0 + 1)

typedef unsigned short ushort_t;
typedef unsigned int   uint_t;
typedef __attribute__((ext_vector_type(8))) short v8s;   // 8 bf16 (4 VGPRs)
typedef __attribute__((ext_vector_type(4))) float v4f;

__device__ __forceinline__ int clampi(int v, int lo, int hi) {
    return v < lo ? lo : (v > hi ? hi : v);
}
__device__ __forceinline__ float bu2f(ushort_t u) {
    union { uint_t i; float f; } v; v.i = ((uint_t)u) << 16; return v.f;
}
__device__ __forceinline__ float blo(uint_t u) { return bu2f((ushort_t)(u & 0xffff)); }
__device__ __forceinline__ float bhi(uint_t u) { return bu2f((ushort_t)(u >> 16)); }
// packed RNE f32x2 -> bf16x2 (low = a, high = b)
__device__ __forceinline__ uint_t cvtpk(float a, float b) {
    uint_t r;
    asm("v_cvt_pk_bf16_f32 %0, %1, %2" : "=v"(r) : "v"(a), "v"(b));
    return r;
}

// LDS weight-table swizzle: logical (row, byte-in-row) -> banked offset.
// XOR bits 4..6 with row&7: ds_read_b128 per fragment becomes 2-way (free).
__device__ __forceinline__ int swz_byte(int row, int byte_in_row) {
    return (row * 256 + byte_in_row) ^ ((row & 7) << 4);
}

// stage W[128][64] transposed+bf16 into LDS rows 0..63 (256-thread version)
__device__ __forceinline__ void stage_w64(ushort_t* shw, const float* __restrict__ W,
                                          int tid) {
    #pragma unroll
    for (int i = 0; i < 4; ++i) {
        const int pi = tid + 256 * i;        // 0..1023
        const int kp = pi >> 4;              // col pair 0..63
        const int n4 = (pi & 15) * 4;        // row group
        const float4 A = *(const float4*)(W + (size_t)(2 * kp) * 64 + n4);
        const float4 B = *(const float4*)(W + (size_t)(2 * kp + 1) * 64 + n4);
        const float Aa[4] = {A.x, A.y, A.z, A.w};
        const float Ba[4] = {B.x, B.y, B.z, B.w};
        #pragma unroll
        for (int j = 0; j < 4; ++j)
            *(uint_t*)((char*)shw + swz_byte(n4 + j, kp * 4)) = cvtpk(Aa[j], Ba[j]);
    }
}
// stage W[128][128] transposed+bf16 into LDS rows 64..191 (256-thread version)
__device__ __forceinline__ void stage_w128(ushort_t* shw, const float* __restrict__ W,
                                           int tid) {
    #pragma unroll
    for (int i = 0; i < 8; ++i) {
        const int pi = tid + 256 * i;        // 0..2047
        const int kp = pi >> 5;              // col pair 0..63
        const int n4 = (pi & 31) * 4;        // row group 0..124
        const float4 A = *(const float4*)(W + (size_t)(2 * kp) * 128 + n4);
        const float4 B = *(const float4*)(W + (size_t)(2 * kp + 1) * 128 + n4);
        const float Aa[4] = {A.x, A.y, A.z, A.w};
        const float Ba[4] = {B.x, B.y, B.z, B.w};
        #pragma unroll
        for (int j = 0; j < 4; ++j)
            *(uint_t*)((char*)shw + swz_byte(64 + n4 + j, kp * 4)) = cvtpk(Aa[j], Ba[j]);
    }
}
// B-fragments for one fp32 row (this lane's table row), k-chunks by q
__device__ __forceinline__ void load_x_rows(const float* __restrict__ X, int rowc,
                                            int q, v8s hfr[4]) {
    #pragma unroll
    for (int c = 0; c < 4; ++c) {
        const float4 f0 = *(const float4*)(X + (size_t)rowc * 128 + 32 * c + 8 * q);
        const float4 f1 = *(const float4*)(X + (size_t)rowc * 128 + 32 * c + 8 * q + 4);
        union { v8s s; uint4 u; } uu;
        uu.u = make_uint4(cvtpk(f0.x, f0.y), cvtpk(f0.z, f0.w),
                          cvtpk(f1.x, f1.y), cvtpk(f1.z, f1.w));
        hfr[c] = uu.s;
    }
}
// full 192-dim MFMA + guarded packed store (attn rows 0..63, msg rows 64..191)
__device__ __forceinline__ void mfma_store(const ushort_t* shw, const v8s hfr[4],
                                           int row, int Nlim,
                                           ushort_t* __restrict__ attn_out,
                                           ushort_t* __restrict__ msg_out,
                                           int m16, int q) {
    #pragma unroll
    for (int t = 0; t < 12; ++t) {
        v4f acc = {0.f, 0.f, 0.f, 0.f};
        #pragma unroll
        for (int c = 0; c < 4; ++c) {
            const v8s wfr = *(const v8s*)((const char*)shw +
                              swz_byte(16 * t + m16, (32 * c + 8 * q) * 2));
            acc = __builtin_amdgcn_mfma_f32_16x16x32_bf16(wfr, hfr[c], acc, 0, 0, 0);
        }
        if (row < Nlim) {
            const uint_t u0 = cvtpk(acc[0], acc[1]);
            const uint_t u1 = cvtpk(acc[2], acc[3]);
            const int dim = 16 * t + 4 * q;
            if (dim < 64)
                *(uint2*)(attn_out + (size_t)row * 64 + dim) = make_uint2(u0, u1);
            else
                *(uint2*)(msg_out + (size_t)row * 128 + (dim - 64)) = make_uint2(u0, u1);
        }
    }
}

// ---------------------------------------------------------------------------
// fused_pre: one kernel, six block roles, all matmul work on MFMA.
// 256 threads/block, 64 rows/block: 816 blocks -> ~3 blocks/CU, 12 waves/CU.
// (round-5's 512-thr variant collapsed to 210 blocks -> Occ 4.9%: reverted)
// ---------------------------------------------------------------------------
__global__ __launch_bounds__(256) void fused_pre(
    const float* __restrict__ hidden, const float* __restrict__ Ws,
    const float* __restrict__ Wh,   const float* __restrict__ rela,
    const float* __restrict__ Wr,   const float* __restrict__ Wtau,
    const float* __restrict__ wt1,  const float* __restrict__ bt1,
    const float* __restrict__ wt2,  const float* __restrict__ bt2,
    const int* __restrict__ q_rel,  const float* __restrict__ WqrW,
    const float* __restrict__ Wqrb, const int* __restrict__ edges,
    ushort_t* __restrict__ node_attn, ushort_t* __restrict__ node_msg,
    ushort_t* __restrict__ rel_attn,  ushort_t* __restrict__ rel_msg,
    ushort_t* __restrict__ dt_attn,   ushort_t* __restrict__ dt_msg,
    ushort_t* __restrict__ Xqr,
    int* __restrict__ flag, int* __restrict__ cnt, int* __restrict__ ovfn)
{
    __shared__ ushort_t shw[192 * 128];          // 48 KiB
    const int bid = blockIdx.x, tid = threadIdx.x;
    const int wid = tid >> 6, lane = tid & 63;
    const int m16 = lane & 15, q = lane >> 4;

    if (bid < NBW_NODE) {
        stage_w64 (shw, Ws, tid);
        stage_w128(shw, Wh, tid);
        __syncthreads();
        const int row  = bid * 64 + wid * 16 + m16;
        const int rowc = row < N_NODE ? row : N_NODE - 1;
        v8s hfr[4];
        load_x_rows(hidden, rowc, q, hfr);
        mfma_store(shw, hfr, row, N_NODE, node_attn, node_msg, m16, q);
    } else if (bid < DB0) {
        stage_w64 (shw, Wr, tid);
        stage_w128(shw, Wh, tid);
        __syncthreads();
        const int row  = (bid - RB0) * 64 + wid * 16 + m16;
        const int rowc = row < N_RELV ? row : N_RELV - 1;
        v8s hfr[4];
        load_x_rows(rela, rowc, q, hfr);
        mfma_store(shw, hfr, row, N_RELV, rel_attn, rel_msg, m16, q);
    } else if (bid < QB0) {
        stage_w64 (shw, Wtau, tid);
        stage_w128(shw, Wh, tid);
        __syncthreads();
        const int row  = (bid - DB0) * 64 + wid * 16 + m16;
        const int rowc = row < N_DT ? row : N_DT - 1;
        const float dtv = (float)(rowc - 365);
        v8s hfr[4];
        #pragma unroll
        for (int c = 0; c < 4; ++c) {
            const int o = 32 * c + 8 * q;
            const float4 w1a = *(const float4*)(wt1 + o), w1b = *(const float4*)(wt1 + o + 4);
            const float4 b1a = *(const float4*)(bt1 + o), b1b = *(const float4*)(bt1 + o + 4);
            const float4 w2a = *(const float4*)(wt2 + o), w2b = *(const float4*)(wt2 + o + 4);
            const float4 b2a = *(const float4*)(bt2 + o), b2b = *(const float4*)(bt2 + o + 4);
            const float h0 = w1a.x * dtv + b1a.x + sinf(w2a.x * dtv + b2a.x);
            const float h1 = w1a.y * dtv + b1a.y + sinf(w2a.y * dtv + b2a.y);
            const float h2 = w1a.z * dtv + b1a.z + sinf(w2a.z * dtv + b2a.z);
            const float h3 = w1a.w * dtv + b1a.w + sinf(w2a.w * dtv + b2a.w);
            const float h4 = w1b.x * dtv + b1b.x + sinf(w2b.x * dtv + b2b.x);
            const float h5 = w1b.y * dtv + b1b.y + sinf(w2b.y * dtv + b2b.y);
            const float h6 = w1b.z * dtv + b1b.z + sinf(w2b.z * dtv + b2b.z);
            const float h7 = w1b.w * dtv + b1b.w + sinf(w2b.w * dtv + b2b.w);
            union { v8s s; uint4 u; } uu;
            uu.u = make_uint4(cvtpk(h0, h1), cvtpk(h2, h3), cvtpk(h4, h5), cvtpk(h6, h7));
            hfr[c] = uu.s;
        }
        mfma_store(shw, hfr, row, N_DT, dt_attn, dt_msg, m16, q);
    } else if (bid < ZB0) {
        // Xqr role (single block): local i64 detect, then attn-only MFMA + bias
        int* ok = (int*)shw;
        if (tid == 0) *ok = 1;
        __syncthreads();
        int badv = 0;
        for (int t = tid; t < 1000; t += 256) {
            const int w = edges[2 * t + 1];
            if (w != 0 && w != -1) badv = 1;
        }
        if (badv) *ok = 0;                       // benign race (all write 0)
        __syncthreads();
        const int i64 = *ok;
        __syncthreads();

        stage_w64(shw, WqrW, tid);
        __syncthreads();
        const int qrow = wid * 16 + m16;         // 0..63, exact
        const int relq = clampi(q_rel[i64 ? 2 * qrow : qrow], 0, N_RELV - 1);
        v8s hfr[4];
        load_x_rows(rela, relq, q, hfr);
        #pragma unroll
        for (int t = 0; t < 4; ++t) {
            v4f acc = {0.f, 0.f, 0.f, 0.f};
            #pragma unroll
            for (int c = 0; c < 4; ++c) {
                const v8s wfr = *(const v8s*)((const char*)shw +
                                  swz_byte(16 * t + m16, (32 * c + 8 * q) * 2));
                acc = __builtin_amdgcn_mfma_f32_16x16x32_bf16(wfr, hfr[c], acc, 0, 0, 0);
            }
            const int dim = 16 * t + 4 * q;
            const float4 bi = *(const float4*)(Wqrb + dim);
            const uint_t u0 = cvtpk(acc[0] + bi.x, acc[1] + bi.y);
            const uint_t u1 = cvtpk(acc[2] + bi.z, acc[3] + bi.w);
            *(uint2*)(Xqr + (size_t)qrow * 64 + dim) = make_uint2(u0, u1);
        }
    } else if (bid < FB0) {
        // cnt zeroing: 13 blocks x 256 threads x 4 int4 (12500 int4 total)
        int4* c4 = (int4*)cnt;
        const int b = (bid - ZB0) * 256 + tid;
        #pragma unroll
        for (int k = 0; k < 4; ++k) {
            const int i4 = b * 4 + k;
            if (i4 < N_NODE / 4) c4[i4] = make_int4(0, 0, 0, 0);
        }
    } else {
        // global i64 flag + ovfn zero
        int* ok = (int*)shw;
        if (tid == 0) *ok = 0;
        __syncthreads();
        int badv = 0;
        for (int t = tid; t < 1000; t += 256) {
            const int w = edges[2 * t + 1];
            if (w != 0 && w != -1) badv = 1;
        }
        if (badv) *ok = 1;
        __syncthreads();
        if (tid == 0) { flag[0] = (*ok == 0) ? 1 : 0; ovfn[0] = 0; }
    }
}

// relu-dot over this lane's 8 dims for one edge
__device__ __forceinline__ float dot8(uint4 xs, uint4 xr, uint4 xt, uint4 xq,
                                      float4 wA, float4 wB)
{
    float s0, s1, v;
    s0 = blo(xs.x) + blo(xr.x) + blo(xt.x) + blo(xq.x);
    s1 = bhi(xs.x) + bhi(xr.x) + bhi(xt.x) + bhi(xq.x);
    v  = fmaxf(s0, 0.f) * wA.x + fmaxf(s1, 0.f) * wA.y;
    s0 = blo(xs.y) + blo(xr.y) + blo(xt.y) + blo(xq.y);
    s1 = bhi(xs.y) + bhi(xr.y) + bhi(xt.y) + bhi(xq.y);
    v += fmaxf(s0, 0.f) * wA.z + fmaxf(s1, 0.f) * wA.w;
    s0 = blo(xs.z) + blo(xr.z) + blo(xt.z) + blo(xq.z);
    s1 = bhi(xs.z) + bhi(xr.z) + bhi(xt.z) + bhi(xq.z);
    v += fmaxf(s0, 0.f) * wB.x + fmaxf(s1, 0.f) * wB.y;
    s0 = blo(xs.w) + blo(xr.w) + blo(xt.w) + blo(xq.w);
    s1 = bhi(xs.w) + bhi(xr.w) + bhi(xt.w) + bhi(xq.w);
    v += fmaxf(s0, 0.f) * wB.z + fmaxf(s1, 0.f) * wB.w;
    return v;
}

// ---------------------------------------------------------------------------
// Phase 1: per-edge alpha. 8 lanes per edge, 4 edges per group (32/wave).
// Xqr + q_tau staged in LDS; sched_barrier(0) pins the 12 global gathers
// above the dot chain. (Round-10 A/B: neutral vs round-6; kept, no harm.)
// meta TRANSPOSED: meta[pos * N_NODE + obj].
// ---------------------------------------------------------------------------
__global__ __launch_bounds__(256) void alpha_scatter(
    const int* __restrict__ edges, const int* __restrict__ q_tau,
    const ushort_t* __restrict__ node_attn, const ushort_t* __restrict__ rel_attn,
    const ushort_t* __restrict__ dt_attn,  const ushort_t* __restrict__ Xqr,
    const float* __restrict__ w_alpha_W, const float* __restrict__ w_alpha_b,
    const int* __restrict__ flag, int* __restrict__ cnt,
    int2* __restrict__ meta, int* __restrict__ ovfn, int4* __restrict__ ovfl)
{
    __shared__ uint_t lXqr[N_QUERY * 32];   // 64 rows x 128 B (bf16)
    __shared__ int    lTq[N_QUERY];

    const int tid = threadIdx.x;
    const int i64 = flag[0];

    // stage Xqr: thread t -> row t>>2, 32-B part t&3 (fully coalesced)
    {
        const int r = tid >> 2, p = tid & 3;
        const uint4 a = *(const uint4*)(Xqr + (size_t)r * ATTN_DIM + p * 16);
        const uint4 b = *(const uint4*)(Xqr + (size_t)r * ATTN_DIM + p * 16 + 8);
        *(uint4*)(lXqr + r * 32 + p * 8)     = a;
        *(uint4*)(lXqr + r * 32 + p * 8 + 4) = b;
    }
    if (tid < N_QUERY) lTq[tid] = q_tau[i64 ? 2 * tid : tid];
    __syncthreads();

    const int g   = tid & 7;
    const int grp = tid >> 3;                       // 0..31
    const int e0r = blockIdx.x * 128 + grp * 4;
    const int e0  = e0r <= N_EDGE - 4 ? e0r : N_EDGE - 4;   // stays 4-aligned

    const float4 wA = *(const float4*)(w_alpha_W + 8 * g);
    const float4 wB = *(const float4*)(w_alpha_W + 8 * g + 4);
    const float  wb = w_alpha_b[0];

    int r0, rel0, tau0, sub0, obj0, r1, rel1, tau1, sub1, obj1;
    int r2, rel2, tau2, sub2, obj2, r3, rel3, tau3, sub3, obj3;
    if (!i64) {
        const int4 ev = *(const int4*)(edges + (size_t)e0 * 7 + 4 * (g < 6 ? g : 6));
        #define GETF(j) __shfl(((j) & 3) == 0 ? ev.x : ((j) & 3) == 1 ? ev.y : \
                               ((j) & 3) == 2 ? ev.z : ev.w, (j) >> 2, 8)
        r0 = GETF(0);  rel0 = GETF(2);  tau0 = GETF(4);  sub0 = GETF(5);  obj0 = GETF(6);
        r1 = GETF(7);  rel1 = GETF(9);  tau1 = GETF(11); sub1 = GETF(12); obj1 = GETF(13);
        r2 = GETF(14); rel2 = GETF(16); tau2 = GETF(18); sub2 = GETF(19); obj2 = GETF(20);
        r3 = GETF(21); rel3 = GETF(23); tau3 = GETF(25); sub3 = GETF(26); obj3 = GETF(27);
        #undef GETF
    } else {
        const int* E0 = edges + (size_t)(e0    ) * 14;
        const int* E1 = edges + (size_t)(e0 + 1) * 14;
        const int* E2 = edges + (size_t)(e0 + 2) * 14;
        const int* E3 = edges + (size_t)(e0 + 3) * 14;
        r0 = E0[0]; rel0 = E0[4]; tau0 = E0[8]; sub0 = E0[10]; obj0 = E0[12];
        r1 = E1[0]; rel1 = E1[4]; tau1 = E1[8]; sub1 = E1[10]; obj1 = E1[12];
        r2 = E2[0]; rel2 = E2[4]; tau2 = E2[8]; sub2 = E2[10]; obj2 = E2[12];
        r3 = E3[0]; rel3 = E3[4]; tau3 = E3[8]; sub3 = E3[10]; obj3 = E3[12];
    }
    r0 = clampi(r0, 0, N_QUERY - 1); rel0 = clampi(rel0, 0, N_RELV - 1);
    sub0 = clampi(sub0, 0, N_NODE - 1); obj0 = clampi(obj0, 0, N_NODE - 1);
    r1 = clampi(r1, 0, N_QUERY - 1); rel1 = clampi(rel1, 0, N_RELV - 1);
    sub1 = clampi(sub1, 0, N_NODE - 1); obj1 = clampi(obj1, 0, N_NODE - 1);
    r2 = clampi(r2, 0, N_QUERY - 1); rel2 = clampi(rel2, 0, N_RELV - 1);
    sub2 = clampi(sub2, 0, N_NODE - 1); obj2 = clampi(obj2, 0, N_NODE - 1);
    r3 = clampi(r3, 0, N_QUERY - 1); rel3 = clampi(rel3, 0, N_RELV - 1);
    sub3 = clampi(sub3, 0, N_NODE - 1); obj3 = clampi(obj3, 0, N_NODE - 1);

    const int tq0 = lTq[r0];
    const int tq1 = lTq[r1];
    const int tq2 = lTq[r2];
    const int tq3 = lTq[r3];
    if (tau0 < 0) tau0 = tq0;
    if (tau1 < 0) tau1 = tq1;
    if (tau2 < 0) tau2 = tq2;
    if (tau3 < 0) tau3 = tq3;
    const int di0 = clampi(tau0 - tq0 + 365, 0, N_DT - 1);
    const int di1 = clampi(tau1 - tq1 + 365, 0, N_DT - 1);
    const int di2 = clampi(tau2 - tq2 + 365, 0, N_DT - 1);
    const int di3 = clampi(tau3 - tq3 + 365, 0, N_DT - 1);

    // 12 independent global gathers issued back-to-back
    const uint4 xs0 = *(const uint4*)(node_attn + (size_t)sub0 * ATTN_DIM + 8 * g);
    const uint4 xr0 = *(const uint4*)(rel_attn + (size_t)rel0 * ATTN_DIM + 8 * g);
    const uint4 xt0 = *(const uint4*)(dt_attn  + (size_t)di0  * ATTN_DIM + 8 * g);
    const uint4 xs1 = *(const uint4*)(node_attn + (size_t)sub1 * ATTN_DIM + 8 * g);
    const uint4 xr1 = *(const uint4*)(rel_attn + (size_t)rel1 * ATTN_DIM + 8 * g);
    const uint4 xt1 = *(const uint4*)(dt_attn  + (size_t)di1  * ATTN_DIM + 8 * g);
    const uint4 xs2 = *(const uint4*)(node_attn + (size_t)sub2 * ATTN_DIM + 8 * g);
    const uint4 xr2 = *(const uint4*)(rel_attn + (size_t)rel2 * ATTN_DIM + 8 * g);
    const uint4 xt2 = *(const uint4*)(dt_attn  + (size_t)di2  * ATTN_DIM + 8 * g);
    const uint4 xs3 = *(const uint4*)(node_attn + (size_t)sub3 * ATTN_DIM + 8 * g);
    const uint4 xr3 = *(const uint4*)(rel_attn + (size_t)rel3 * ATTN_DIM + 8 * g);
    const uint4 xt3 = *(const uint4*)(dt_attn  + (size_t)di3  * ATTN_DIM + 8 * g);
    // Xqr from LDS (fast, ~free banks: 64 lanes over 32 banks = 2/bank)
    const uint4 xq0 = *(const uint4*)(lXqr + r0 * 32 + 4 * g);
    const uint4 xq1 = *(const uint4*)(lXqr + r1 * 32 + 4 * g);
    const uint4 xq2 = *(const uint4*)(lXqr + r2 * 32 + 4 * g);
    const uint4 xq3 = *(const uint4*)(lXqr + r3 * 32 + 4 * g);

    // keep all loads ABOVE, dots BELOW: forces 12-deep MLP per wave
    __builtin_amdgcn_sched_barrier(0);

    float v0 = dot8(xs0, xr0, xt0, xq0, wA, wB);
    float v1 = dot8(xs1, xr1, xt1, xq1, wA, wB);
    float v2 = dot8(xs2, xr2, xt2, xq2, wA, wB);
    float v3 = dot8(xs3, xr3, xt3, xq3, wA, wB);

    #pragma unroll
    for (int off = 4; off > 0; off >>= 1) {
        v0 += __shfl_xor(v0, off, 8);
        v1 += __shfl_xor(v1, off, 8);
        v2 += __shfl_xor(v2, off, 8);
        v3 += __shfl_xor(v3, off, 8);
    }

    if (g < 4 && e0r + g < N_EDGE) {
        const float vg  = g == 0 ? v0 : (g == 1 ? v1 : (g == 2 ? v2 : v3));
        const int objg  = g == 0 ? obj0 : (g == 1 ? obj1 : (g == 2 ? obj2 : obj3));
        const int subg  = g == 0 ? sub0 : (g == 1 ? sub1 : (g == 2 ? sub2 : sub3));
        const int dig   = g == 0 ? di0  : (g == 1 ? di1  : (g == 2 ? di2  : di3));
        const int relg  = g == 0 ? rel0 : (g == 1 ? rel1 : (g == 2 ? rel2 : rel3));
        const float alpha = 1.f / (1.f + __expf(-(vg + wb)));
        const int pos = atomicAdd(&cnt[objg], 1);
        if (pos < CAP) {
            const uint_t px = (uint_t)subg | ((uint_t)dig << 17) | ((uint_t)(relg & 31) << 27);
            const uint_t py = (uint_t)(relg >> 5) |
                              ((uint_t)__half_as_ushort(__float2half_rn(alpha)) << 16);
            meta[(size_t)pos * N_NODE + objg] = make_int2((int)px, (int)py);
        } else {
            const int ov = atomicAdd(ovfn, 1);
            if (ov < N_EDGE)
                ovfl[ov] = make_int4(subg | (dig << 17), relg | (objg << 9),
                                     __float_as_int(alpha), 0);
        }
    }
}

// ---------------------------------------------------------------------------
// Phase 2: per-node aggregation. QUARTER-wave (16 lanes) per edge with uint4
// gathers; 8-edge unroll; XCD-chunked swizzle. NEW: software-pipelined meta
// double-buffer — the meta load for iteration j+8 issues at the top of
// iteration j, hiding its L2 latency under the current 6 gathers + VALU.
// (Round-1 agg VGPR=20 showed the compiler was NOT pipelining; each
// iteration paid meta-latency + gather-latency serially.)
// Prefetch index clamps to slot 0 on the final iteration; the prefetched
// value is never accumulated, and all meta reads stay inside the workspace.
// ---------------------------------------------------------------------------
__device__ __forceinline__ void gather3(
    int2 m, int l16,
    const ushort_t* __restrict__ node_msg, const ushort_t* __restrict__ rel_msg,
    const ushort_t* __restrict__ dt_msg,
    uint4& A, uint4& B, uint4& T, float& al)
{
    const int sub = m.x & 0x1FFFF;
    const int di  = ((uint_t)m.x >> 17) & 0x3FF;
    const int rel = (((uint_t)m.x >> 27) & 31) | (((uint_t)m.y & 0xF) << 5);
    al = __half2float(__ushort_as_half((ushort_t)((uint_t)m.y >> 16)));
    A = *(const uint4*)(node_msg + (size_t)sub * 128 + 8 * l16);
    B = *(const uint4*)(rel_msg  + (size_t)rel * 128 + 8 * l16);
    T = *(const uint4*)(dt_msg   + (size_t)di  * 128 + 8 * l16);
}
__device__ __forceinline__ void accum8(
    uint4 A, uint4 B, uint4 T, float al,
    float& a0, float& a1, float& a2, float& a3,
    float& a4, float& a5, float& a6, float& a7)
{
    a0 += al * (blo(A.x) + blo(B.x) + blo(T.x));
    a1 += al * (bhi(A.x) + bhi(B.x) + bhi(T.x));
    a2 += al * (blo(A.y) + blo(B.y) + blo(T.y));
    a3 += al * (bhi(A.y) + bhi(B.y) + bhi(T.y));
    a4 += al * (blo(A.z) + blo(B.z) + blo(T.z));
    a5 += al * (bhi(A.z) + bhi(B.z) + bhi(T.z));
    a6 += al * (blo(A.w) + blo(B.w) + blo(T.w));
    a7 += al * (bhi(A.w) + bhi(B.w) + bhi(T.w));
}

__global__ __launch_bounds__(256) void agg_kernel(
    const int* __restrict__ cnt, const int2* __restrict__ meta,
    const int* __restrict__ ovfn, const int4* __restrict__ ovfl,
    const ushort_t* __restrict__ node_msg, const ushort_t* __restrict__ rel_msg,
    const ushort_t* __restrict__ dt_msg, float* __restrict__ out)
{
    // bijective chunked XCD swizzle (m204 form)
    const int nblk = gridDim.x;                  // 12500
    const int bq = nblk >> 3, br = nblk & 7;
    const int xcd = blockIdx.x & 7, idx = blockIdx.x >> 3;
    const int bswz = (xcd < br ? xcd * (bq + 1)
                               : br * (bq + 1) + (xcd - br) * bq) + idx;

    const int lane = threadIdx.x & 63;
    const int sg   = lane >> 4;                  // 0..3: edge slot in quad
    const int l16  = lane & 15;                  // covers dims 8*l16..+7
    const int n    = bswz * 4 + (threadIdx.x >> 6);

    int m = cnt[n]; if (m > CAP) m = CAP;
    float a0 = 0.f, a1 = 0.f, a2 = 0.f, a3 = 0.f;
    float a4 = 0.f, a5 = 0.f, a6 = 0.f, a7 = 0.f;

    int j = 0;
    if (m >= 8) {
        // prologue: prefetch first meta pair
        int2 mA = meta[(size_t)(0 + sg) * N_NODE + n];
        int2 mB = meta[(size_t)(4 + sg) * N_NODE + n];
        for (; j + 7 < m; j += 8) {
            const int2 ca = mA, cb = mB;
            // prefetch NEXT iteration's meta (clamped to valid slot 0;
            // value unused on the last pass)
            const int ia = (j + 8  + sg < m) ? (j + 8  + sg) : 0;
            const int ib = (j + 12 + sg < m) ? (j + 12 + sg) : 0;
            mA = meta[(size_t)ia * N_NODE + n];
            mB = meta[(size_t)ib * N_NODE + n];
            uint4 Aa, Ba, Ta; float wa;
            uint4 Ab, Bb, Tb; float wbb;
            gather3(ca, l16, node_msg, rel_msg, dt_msg, Aa, Ba, Ta, wa);
            gather3(cb, l16, node_msg, rel_msg, dt_msg, Ab, Bb, Tb, wbb);
            accum8(Aa, Ba, Ta, wa, a0, a1, a2, a3, a4, a5, a6, a7);
            accum8(Ab, Bb, Tb, wbb, a0, a1, a2, a3, a4, a5, a6, a7);
        }
    }
    for (; j < m; j += 4) {                      // masked tail (per sub-group)
        if (j + sg < m) {
            const int2 ma = meta[(size_t)(j + sg) * N_NODE + n];
            uint4 Aa, Ba, Ta; float wa;
            gather3(ma, l16, node_msg, rel_msg, dt_msg, Aa, Ba, Ta, wa);
            accum8(Aa, Ba, Ta, wa, a0, a1, a2, a3, a4, a5, a6, a7);
        }
    }

    // overflow entries (normally none): scan, filter by obj == n, sg 0 only
    int nov = ovfn[0]; if (nov > N_EDGE) nov = N_EDGE;
    for (int i = 0; i < nov; ++i) {
        const int4 mo = ovfl[i];
        const int objo = (int)((uint_t)mo.y >> 9);
        if (objo != n || sg != 0) continue;
        const int subo = mo.x & 0x1FFFF;
        const int dio  = (int)((uint_t)mo.x >> 17);
        const int relo = mo.y & 0x1FF;
        const float alo = __int_as_float(mo.z);
        const uint4 A = *(const uint4*)(node_msg + (size_t)subo * 128 + 8 * l16);
        const uint4 B = *(const uint4*)(rel_msg  + (size_t)relo * 128 + 8 * l16);
        const uint4 T = *(const uint4*)(dt_msg   + (size_t)dio  * 128 + 8 * l16);
        accum8(A, B, T, alo, a0, a1, a2, a3, a4, a5, a6, a7);
    }

    // combine the 4 sub-groups (lane ^16, ^32)
    a0 += __shfl_xor(a0, 16, 64); a0 += __shfl_xor(a0, 32, 64);
    a1 += __shfl_xor(a1, 16, 64); a1 += __shfl_xor(a1, 32, 64);
    a2 += __shfl_xor(a2, 16, 64); a2 += __shfl_xor(a2, 32, 64);
    a3 += __shfl_xor(a3, 16, 64); a3 += __shfl_xor(a3, 32, 64);
    a4 += __shfl_xor(a4, 16, 64); a4 += __shfl_xor(a4, 32, 64);
    a5 += __shfl_xor(a5, 16, 64); a5 += __shfl_xor(a5, 32, 64);
    a6 += __shfl_xor(a6, 16, 64); a6 += __shfl_xor(a6, 32, 64);
    a7 += __shfl_xor(a7, 16, 64); a7 += __shfl_xor(a7, 32, 64);

    if (sg == 0) {
        float4 o0; o0.x = a0; o0.y = a1; o0.z = a2; o0.w = a3;
        float4 o1; o1.x = a4; o1.y = a5; o1.z = a6; o1.w = a7;
        *(float4*)(out + (size_t)n * OUT_DIM + 8 * l16)     = o0;
        *(float4*)(out + (size_t)n * OUT_DIM + 8 * l16 + 4) = o1;
    }
}

// ---------------------------------------------------------------------------
// Fallback: single-pass atomic edge kernel (small-workspace path).
// ---------------------------------------------------------------------------
__device__ __forceinline__ void parse_edge(const int* __restrict__ edges, int e,
                                           int i64, int& r, int& rel, int& tau,
                                           int& sub, int& obj) {
    if (i64) {
        const int* E = edges + (size_t)e * 14;
        r = E[0]; rel = E[4]; tau = E[8]; sub = E[10]; obj = E[12];
    } else {
        const int* E = edges + (size_t)e * 7;
        r = E[0]; rel = E[2]; tau = E[4]; sub = E[5]; obj = E[6];
    }
    r   = clampi(r,   0, N_QUERY - 1);
    rel = clampi(rel, 0, N_RELV - 1);
    sub = clampi(sub, 0, N_NODE - 1);
    obj = clampi(obj, 0, N_NODE - 1);
}

__global__ __launch_bounds__(256) void edge_atomic_kernel(
    const int* __restrict__ edges, const int* __restrict__ q_tau,
    const ushort_t* __restrict__ node_attn, const ushort_t* __restrict__ node_msg,
    const ushort_t* __restrict__ rel_attn,  const ushort_t* __restrict__ rel_msg,
    const ushort_t* __restrict__ dt_attn,   const ushort_t* __restrict__ dt_msg,
    const ushort_t* __restrict__ Xqr,
    const float* __restrict__ w_alpha_W, const float* __restrict__ w_alpha_b,
    const int* __restrict__ flag, float* __restrict__ out)
{
    const int lane = threadIdx.x & 63;
    const int e    = blockIdx.x * 4 + (threadIdx.x >> 6);
    const int i64  = flag[0];

    int r, rel, tau, sub, obj;
    parse_edge(edges, e, i64, r, rel, tau, sub, obj);
    const int tq = q_tau[i64 ? 2 * r : r];
    if (tau < 0) tau = tq;
    const int di = clampi(tau - tq + 365, 0, N_DT - 1);

    const float xs = bu2f(node_attn[(size_t)sub * ATTN_DIM + lane]);
    const float xr = bu2f(rel_attn[(size_t)rel * ATTN_DIM + lane]);
    const float xt = bu2f(dt_attn[(size_t)di  * ATTN_DIM + lane]);
    const float xq = bu2f(Xqr[(size_t)r * ATTN_DIM + lane]);

    float v = fmaxf(xs + xr + xq + xt, 0.f) * w_alpha_W[lane];
    #pragma unroll
    for (int off = 32; off > 0; off >>= 1)
        v += __shfl_down(v, off, 64);
    v = __shfl(v, 0, 64);
    const float alpha = 1.f / (1.f + __expf(-(v + w_alpha_b[0])));

    const uint_t am = *(const uint_t*)(node_msg + (size_t)sub * 128 + 2 * lane);
    const uint_t bm = *(const uint_t*)(rel_msg  + (size_t)rel * 128 + 2 * lane);
    const uint_t tm = *(const uint_t*)(dt_msg   + (size_t)di  * 128 + 2 * lane);
    const float mx = blo(am) + blo(bm) + blo(tm);
    const float my = bhi(am) + bhi(bm) + bhi(tm);

    float* dst = out + (size_t)obj * OUT_DIM;
    atomicAdd(dst + 2 * lane,     alpha * mx);
    atomicAdd(dst + 2 * lane + 1, alpha * my);
}

// ===========================================================================
extern "C" void kernel_launch(void* const* d_in, const int* in_sizes, int n_in,
                              void* d_out, int out_size, void* d_ws, size_t ws_size,
                              hipStream_t stream)
{
    const int*   q_rel  = (const int*)d_in[1];
    const int*   q_tau  = (const int*)d_in[2];
    const float* hidden = (const float*)d_in[3];
    const int*   edges  = (const int*)d_in[4];
    const float* rela   = (const float*)d_in[7];
    const float* Ws     = (const float*)d_in[8];
    const float* Wr     = (const float*)d_in[9];
    const float* WqrW   = (const float*)d_in[10];
    const float* Wqrb   = (const float*)d_in[11];
    const float* Wtau   = (const float*)d_in[12];
    const float* waW    = (const float*)d_in[13];
    const float* wab    = (const float*)d_in[14];
    const float* Wh     = (const float*)d_in[15];
    const float* wt1    = (const float*)d_in[16];
    const float* bt1    = (const float*)d_in[17];
    const float* wt2    = (const float*)d_in[18];
    const float* bt2    = (const float*)d_in[19];
    float* out = (float*)d_out;

    // --- workspace carve (256-B aligned chunks) ---
    char* p = (char*)d_ws;
    size_t off = 0;
    auto carve = [&](size_t bytes) {
        char* q = p + off;
        off = (off + bytes + 255) & ~(size_t)255;
        return q;
    };
    int*      flag      = (int*)     carve(64);
    int*      cnt       = (int*)     carve((size_t)N_NODE * 4);
    int*      ovfn      = (int*)     carve(64);
    ushort_t* XqrB      = (ushort_t*)carve((size_t)N_QUERY * ATTN_DIM * 2);
    ushort_t* rel_attn  = (ushort_t*)carve((size_t)N_RELV * ATTN_DIM * 2);
    ushort_t* rel_msg   = (ushort_t*)carve((size_t)N_RELV * OUT_DIM * 2);
    ushort_t* dt_attn   = (ushort_t*)carve((size_t)N_DT * ATTN_DIM * 2);
    ushort_t* dt_msg    = (ushort_t*)carve((size_t)N_DT * OUT_DIM * 2);
    ushort_t* node_attn = (ushort_t*)carve((size_t)N_NODE * ATTN_DIM * 2);
    ushort_t* node_msg  = (ushort_t*)carve((size_t)N_NODE * OUT_DIM * 2);
    int2*     meta      = (int2*)    carve((size_t)N_NODE * CAP * 8);
    int4*     ovfl      = (int4*)    carve((size_t)N_EDGE * 16);
    const size_t need_full = off;

    fused_pre<<<NB_TOT, 256, 0, stream>>>(
        hidden, Ws, Wh, rela, Wr, Wtau, wt1, bt1, wt2, bt2,
        q_rel, WqrW, Wqrb, edges,
        node_attn, node_msg, rel_attn, rel_msg, dt_attn, dt_msg, XqrB,
        flag, cnt, ovfn);

    if (ws_size >= need_full) {
        alpha_scatter<<<(N_EDGE + 127) / 128, 256, 0, stream>>>(
            edges, q_tau, node_attn, rel_attn, dt_attn, XqrB,
            waW, wab, flag, cnt, meta, ovfn, ovfl);
        agg_kernel<<<N_NODE / 4, 256, 0, stream>>>(cnt, meta, ovfn, ovfl,
                                                   node_msg, rel_msg, dt_msg, out);
    } else {
        (void)hipMemsetAsync(out, 0, (size_t)out_size * sizeof(float), stream);
        edge_atomic_kernel<<<N_EDGE / 4, 256, 0, stream>>>(edges, q_tau,
                                                           node_attn, node_msg,
                                                           rel_attn, rel_msg,
                                                           dt_attn, dt_msg, XqrB,
                                                           waW, wab, flag, out);
    }
}

// Round 17
// 190.755 us; speedup vs baseline: 1.0152x; 1.0152x over previous
//
#include <hip/hip_runtime.h>
#include <hip/hip_fp16.h>

#define IN_DIM   128
#define OUT_DIM  128
#define ATTN_DIM 64
#define N_RELV   401
#define N_NODE   50000
#define N_EDGE   500000
#define N_QUERY  64
#define N_DT     731
#define CAP      40       // padded bucket capacity (deg ~ Poisson(10); P(>=40) ~ 1e-11)

// fused_pre block roles (256 threads/block; node blocks cover 64 rows)
#define NBW_NODE 782              // ceil(50000/64)
#define NBW_REL  7                // 7*64 = 448 >= 401
#define NBW_DT   12               // 12*64 = 768 >= 731
#define NBW_QR   1                // 64 queries
#define NBW_ZERO 13               // cnt zeroing
#define RB0      NBW_NODE
#define DB0      (NBW_NODE + NBW_REL)
#define QB0      (DB0 + NBW_DT)
#define ZB0      (QB0 + NBW_QR)
#define FB0      (ZB0 + NBW_ZERO)
#define NB_TOT   (FB0 + 1)

typedef unsigned short ushort_t;
typedef unsigned int   uint_t;
typedef __attribute__((ext_vector_type(8))) short v8s;   // 8 bf16 (4 VGPRs)
typedef __attribute__((ext_vector_type(4))) float v4f;

__device__ __forceinline__ int clampi(int v, int lo, int hi) {
    return v < lo ? lo : (v > hi ? hi : v);
}
__device__ __forceinline__ float bu2f(ushort_t u) {
    union { uint_t i; float f; } v; v.i = ((uint_t)u) << 16; return v.f;
}
__device__ __forceinline__ float blo(uint_t u) { return bu2f((ushort_t)(u & 0xffff)); }
__device__ __forceinline__ float bhi(uint_t u) { return bu2f((ushort_t)(u >> 16)); }
// packed RNE f32x2 -> bf16x2 (low = a, high = b)
__device__ __forceinline__ uint_t cvtpk(float a, float b) {
    uint_t r;
    asm("v_cvt_pk_bf16_f32 %0, %1, %2" : "=v"(r) : "v"(a), "v"(b));
    return r;
}
// packed RTZ f32x2 -> f16x2 (low = a, high = b). f16 (10 mant bits) beats
// bf16 (8) for the msg tables (values <= ~1.2e3 << 65504).
__device__ __forceinline__ uint_t pkrtz(float a, float b) {
    uint_t r;
    asm("v_cvt_pkrtz_f16_f32 %0, %1, %2" : "=v"(r) : "v"(a), "v"(b));
    return r;
}
__device__ __forceinline__ __half2 u2h2(uint_t u) {
    union { uint_t u; __half2 h; } v; v.u = u; return v.h;
}

// LDS weight-table swizzle: logical (row, byte-in-row) -> banked offset.
// XOR bits 4..6 with row&7: ds_read_b128 per fragment becomes 2-way (free).
__device__ __forceinline__ int swz_byte(int row, int byte_in_row) {
    return (row * 256 + byte_in_row) ^ ((row & 7) << 4);
}

// stage W[128][64] transposed+bf16 into LDS rows 0..63 (256-thread version)
__device__ __forceinline__ void stage_w64(ushort_t* shw, const float* __restrict__ W,
                                          int tid) {
    #pragma unroll
    for (int i = 0; i < 4; ++i) {
        const int pi = tid + 256 * i;        // 0..1023
        const int kp = pi >> 4;              // col pair 0..63
        const int n4 = (pi & 15) * 4;        // row group
        const float4 A = *(const float4*)(W + (size_t)(2 * kp) * 64 + n4);
        const float4 B = *(const float4*)(W + (size_t)(2 * kp + 1) * 64 + n4);
        const float Aa[4] = {A.x, A.y, A.z, A.w};
        const float Ba[4] = {B.x, B.y, B.z, B.w};
        #pragma unroll
        for (int j = 0; j < 4; ++j)
            *(uint_t*)((char*)shw + swz_byte(n4 + j, kp * 4)) = cvtpk(Aa[j], Ba[j]);
    }
}
// stage W[128][128] transposed+bf16 into LDS rows 64..191 (256-thread version)
__device__ __forceinline__ void stage_w128(ushort_t* shw, const float* __restrict__ W,
                                           int tid) {
    #pragma unroll
    for (int i = 0; i < 8; ++i) {
        const int pi = tid + 256 * i;        // 0..2047
        const int kp = pi >> 5;              // col pair 0..63
        const int n4 = (pi & 31) * 4;        // row group 0..124
        const float4 A = *(const float4*)(W + (size_t)(2 * kp) * 128 + n4);
        const float4 B = *(const float4*)(W + (size_t)(2 * kp + 1) * 128 + n4);
        const float Aa[4] = {A.x, A.y, A.z, A.w};
        const float Ba[4] = {B.x, B.y, B.z, B.w};
        #pragma unroll
        for (int j = 0; j < 4; ++j)
            *(uint_t*)((char*)shw + swz_byte(64 + n4 + j, kp * 4)) = cvtpk(Aa[j], Ba[j]);
    }
}
// B-fragments for one fp32 row (this lane's table row), k-chunks by q
__device__ __forceinline__ void load_x_rows(const float* __restrict__ X, int rowc,
                                            int q, v8s hfr[4]) {
    #pragma unroll
    for (int c = 0; c < 4; ++c) {
        const float4 f0 = *(const float4*)(X + (size_t)rowc * 128 + 32 * c + 8 * q);
        const float4 f1 = *(const float4*)(X + (size_t)rowc * 128 + 32 * c + 8 * q + 4);
        union { v8s s; uint4 u; } uu;
        uu.u = make_uint4(cvtpk(f0.x, f0.y), cvtpk(f0.z, f0.w),
                          cvtpk(f1.x, f1.y), cvtpk(f1.z, f1.w));
        hfr[c] = uu.s;
    }
}
// full 192-dim MFMA + guarded packed store.
// attn rows 0..63 -> bf16 out; msg rows 64..191 -> F16 out (agg packed math).
__device__ __forceinline__ void mfma_store(const ushort_t* shw, const v8s hfr[4],
                                           int row, int Nlim,
                                           ushort_t* __restrict__ attn_out,
                                           ushort_t* __restrict__ msg_out,
                                           int m16, int q) {
    #pragma unroll
    for (int t = 0; t < 12; ++t) {
        v4f acc = {0.f, 0.f, 0.f, 0.f};
        #pragma unroll
        for (int c = 0; c < 4; ++c) {
            const v8s wfr = *(const v8s*)((const char*)shw +
                              swz_byte(16 * t + m16, (32 * c + 8 * q) * 2));
            acc = __builtin_amdgcn_mfma_f32_16x16x32_bf16(wfr, hfr[c], acc, 0, 0, 0);
        }
        if (row < Nlim) {
            const int dim = 16 * t + 4 * q;
            if (dim < 64) {
                const uint_t u0 = cvtpk(acc[0], acc[1]);
                const uint_t u1 = cvtpk(acc[2], acc[3]);
                *(uint2*)(attn_out + (size_t)row * 64 + dim) = make_uint2(u0, u1);
            } else {
                const uint_t u0 = pkrtz(acc[0], acc[1]);
                const uint_t u1 = pkrtz(acc[2], acc[3]);
                *(uint2*)(msg_out + (size_t)row * 128 + (dim - 64)) = make_uint2(u0, u1);
            }
        }
    }
}

// ---------------------------------------------------------------------------
// fused_pre: one kernel, six block roles, all matmul work on MFMA.
// 256 threads/block, 64 rows/block: 816 blocks -> ~3 blocks/CU, 12 waves/CU.
// ---------------------------------------------------------------------------
__global__ __launch_bounds__(256) void fused_pre(
    const float* __restrict__ hidden, const float* __restrict__ Ws,
    const float* __restrict__ Wh,   const float* __restrict__ rela,
    const float* __restrict__ Wr,   const float* __restrict__ Wtau,
    const float* __restrict__ wt1,  const float* __restrict__ bt1,
    const float* __restrict__ wt2,  const float* __restrict__ bt2,
    const int* __restrict__ q_rel,  const float* __restrict__ WqrW,
    const float* __restrict__ Wqrb, const int* __restrict__ edges,
    ushort_t* __restrict__ node_attn, ushort_t* __restrict__ node_msg,
    ushort_t* __restrict__ rel_attn,  ushort_t* __restrict__ rel_msg,
    ushort_t* __restrict__ dt_attn,   ushort_t* __restrict__ dt_msg,
    ushort_t* __restrict__ Xqr,
    int* __restrict__ flag, int* __restrict__ cnt, int* __restrict__ ovfn)
{
    __shared__ ushort_t shw[192 * 128];          // 48 KiB
    const int bid = blockIdx.x, tid = threadIdx.x;
    const int wid = tid >> 6, lane = tid & 63;
    const int m16 = lane & 15, q = lane >> 4;

    if (bid < NBW_NODE) {
        stage_w64 (shw, Ws, tid);
        stage_w128(shw, Wh, tid);
        __syncthreads();
        const int row  = bid * 64 + wid * 16 + m16;
        const int rowc = row < N_NODE ? row : N_NODE - 1;
        v8s hfr[4];
        load_x_rows(hidden, rowc, q, hfr);
        mfma_store(shw, hfr, row, N_NODE, node_attn, node_msg, m16, q);
    } else if (bid < DB0) {
        stage_w64 (shw, Wr, tid);
        stage_w128(shw, Wh, tid);
        __syncthreads();
        const int row  = (bid - RB0) * 64 + wid * 16 + m16;
        const int rowc = row < N_RELV ? row : N_RELV - 1;
        v8s hfr[4];
        load_x_rows(rela, rowc, q, hfr);
        mfma_store(shw, hfr, row, N_RELV, rel_attn, rel_msg, m16, q);
    } else if (bid < QB0) {
        stage_w64 (shw, Wtau, tid);
        stage_w128(shw, Wh, tid);
        __syncthreads();
        const int row  = (bid - DB0) * 64 + wid * 16 + m16;
        const int rowc = row < N_DT ? row : N_DT - 1;
        const float dtv = (float)(rowc - 365);
        v8s hfr[4];
        #pragma unroll
        for (int c = 0; c < 4; ++c) {
            const int o = 32 * c + 8 * q;
            const float4 w1a = *(const float4*)(wt1 + o), w1b = *(const float4*)(wt1 + o + 4);
            const float4 b1a = *(const float4*)(bt1 + o), b1b = *(const float4*)(bt1 + o + 4);
            const float4 w2a = *(const float4*)(wt2 + o), w2b = *(const float4*)(wt2 + o + 4);
            const float4 b2a = *(const float4*)(bt2 + o), b2b = *(const float4*)(bt2 + o + 4);
            const float h0 = w1a.x * dtv + b1a.x + sinf(w2a.x * dtv + b2a.x);
            const float h1 = w1a.y * dtv + b1a.y + sinf(w2a.y * dtv + b2a.y);
            const float h2 = w1a.z * dtv + b1a.z + sinf(w2a.z * dtv + b2a.z);
            const float h3 = w1a.w * dtv + b1a.w + sinf(w2a.w * dtv + b2a.w);
            const float h4 = w1b.x * dtv + b1b.x + sinf(w2b.x * dtv + b2b.x);
            const float h5 = w1b.y * dtv + b1b.y + sinf(w2b.y * dtv + b2b.y);
            const float h6 = w1b.z * dtv + b1b.z + sinf(w2b.z * dtv + b2b.z);
            const float h7 = w1b.w * dtv + b1b.w + sinf(w2b.w * dtv + b2b.w);
            union { v8s s; uint4 u; } uu;
            uu.u = make_uint4(cvtpk(h0, h1), cvtpk(h2, h3), cvtpk(h4, h5), cvtpk(h6, h7));
            hfr[c] = uu.s;
        }
        mfma_store(shw, hfr, row, N_DT, dt_attn, dt_msg, m16, q);
    } else if (bid < ZB0) {
        // Xqr role (single block): local i64 detect, then attn-only MFMA + bias
        int* ok = (int*)shw;
        if (tid == 0) *ok = 1;
        __syncthreads();
        int badv = 0;
        for (int t = tid; t < 1000; t += 256) {
            const int w = edges[2 * t + 1];
            if (w != 0 && w != -1) badv = 1;
        }
        if (badv) *ok = 0;                       // benign race (all write 0)
        __syncthreads();
        const int i64 = *ok;
        __syncthreads();

        stage_w64(shw, WqrW, tid);
        __syncthreads();
        const int qrow = wid * 16 + m16;         // 0..63, exact
        const int relq = clampi(q_rel[i64 ? 2 * qrow : qrow], 0, N_RELV - 1);
        v8s hfr[4];
        load_x_rows(rela, relq, q, hfr);
        #pragma unroll
        for (int t = 0; t < 4; ++t) {
            v4f acc = {0.f, 0.f, 0.f, 0.f};
            #pragma unroll
            for (int c = 0; c < 4; ++c) {
                const v8s wfr = *(const v8s*)((const char*)shw +
                                  swz_byte(16 * t + m16, (32 * c + 8 * q) * 2));
                acc = __builtin_amdgcn_mfma_f32_16x16x32_bf16(wfr, hfr[c], acc, 0, 0, 0);
            }
            const int dim = 16 * t + 4 * q;
            const float4 bi = *(const float4*)(Wqrb + dim);
            const uint_t u0 = cvtpk(acc[0] + bi.x, acc[1] + bi.y);
            const uint_t u1 = cvtpk(acc[2] + bi.z, acc[3] + bi.w);
            *(uint2*)(Xqr + (size_t)qrow * 64 + dim) = make_uint2(u0, u1);
        }
    } else if (bid < FB0) {
        // cnt zeroing: 13 blocks x 256 threads x 4 int4 (12500 int4 total)
        int4* c4 = (int4*)cnt;
        const int b = (bid - ZB0) * 256 + tid;
        #pragma unroll
        for (int k = 0; k < 4; ++k) {
            const int i4 = b * 4 + k;
            if (i4 < N_NODE / 4) c4[i4] = make_int4(0, 0, 0, 0);
        }
    } else {
        // global i64 flag + ovfn zero
        int* ok = (int*)shw;
        if (tid == 0) *ok = 0;
        __syncthreads();
        int badv = 0;
        for (int t = tid; t < 1000; t += 256) {
            const int w = edges[2 * t + 1];
            if (w != 0 && w != -1) badv = 1;
        }
        if (badv) *ok = 1;
        __syncthreads();
        if (tid == 0) { flag[0] = (*ok == 0) ? 1 : 0; ovfn[0] = 0; }
    }
}

// relu-dot over this lane's 8 dims for one edge (attn tables: bf16)
__device__ __forceinline__ float dot8(uint4 xs, uint4 xr, uint4 xt, uint4 xq,
                                      float4 wA, float4 wB)
{
    float s0, s1, v;
    s0 = blo(xs.x) + blo(xr.x) + blo(xt.x) + blo(xq.x);
    s1 = bhi(xs.x) + bhi(xr.x) + bhi(xt.x) + bhi(xq.x);
    v  = fmaxf(s0, 0.f) * wA.x + fmaxf(s1, 0.f) * wA.y;
    s0 = blo(xs.y) + blo(xr.y) + blo(xt.y) + blo(xq.y);
    s1 = bhi(xs.y) + bhi(xr.y) + bhi(xt.y) + bhi(xq.y);
    v += fmaxf(s0, 0.f) * wA.z + fmaxf(s1, 0.f) * wA.w;
    s0 = blo(xs.z) + blo(xr.z) + blo(xt.z) + blo(xq.z);
    s1 = bhi(xs.z) + bhi(xr.z) + bhi(xt.z) + bhi(xq.z);
    v += fmaxf(s0, 0.f) * wB.x + fmaxf(s1, 0.f) * wB.y;
    s0 = blo(xs.w) + blo(xr.w) + blo(xt.w) + blo(xq.w);
    s1 = bhi(xs.w) + bhi(xr.w) + bhi(xt.w) + bhi(xq.w);
    v += fmaxf(s0, 0.f) * wB.z + fmaxf(s1, 0.f) * wB.w;
    return v;
}

// ---------------------------------------------------------------------------
// Phase 1: per-edge alpha. 8 lanes per edge, 4 edges per group (32/wave).
// Xqr + q_tau staged in LDS; sched_barrier(0) pins the 12 global gathers.
// meta TRANSPOSED: meta[pos * N_NODE + obj].
// ---------------------------------------------------------------------------
__global__ __launch_bounds__(256) void alpha_scatter(
    const int* __restrict__ edges, const int* __restrict__ q_tau,
    const ushort_t* __restrict__ node_attn, const ushort_t* __restrict__ rel_attn,
    const ushort_t* __restrict__ dt_attn,  const ushort_t* __restrict__ Xqr,
    const float* __restrict__ w_alpha_W, const float* __restrict__ w_alpha_b,
    const int* __restrict__ flag, int* __restrict__ cnt,
    int2* __restrict__ meta, int* __restrict__ ovfn, int4* __restrict__ ovfl)
{
    __shared__ uint_t lXqr[N_QUERY * 32];   // 64 rows x 128 B (bf16)
    __shared__ int    lTq[N_QUERY];

    const int tid = threadIdx.x;
    const int i64 = flag[0];

    // stage Xqr: thread t -> row t>>2, 32-B part t&3 (fully coalesced)
    {
        const int r = tid >> 2, p = tid & 3;
        const uint4 a = *(const uint4*)(Xqr + (size_t)r * ATTN_DIM + p * 16);
        const uint4 b = *(const uint4*)(Xqr + (size_t)r * ATTN_DIM + p * 16 + 8);
        *(uint4*)(lXqr + r * 32 + p * 8)     = a;
        *(uint4*)(lXqr + r * 32 + p * 8 + 4) = b;
    }
    if (tid < N_QUERY) lTq[tid] = q_tau[i64 ? 2 * tid : tid];
    __syncthreads();

    const int g   = tid & 7;
    const int grp = tid >> 3;                       // 0..31
    const int e0r = blockIdx.x * 128 + grp * 4;
    const int e0  = e0r <= N_EDGE - 4 ? e0r : N_EDGE - 4;   // stays 4-aligned

    const float4 wA = *(const float4*)(w_alpha_W + 8 * g);
    const float4 wB = *(const float4*)(w_alpha_W + 8 * g + 4);
    const float  wb = w_alpha_b[0];

    int r0, rel0, tau0, sub0, obj0, r1, rel1, tau1, sub1, obj1;
    int r2, rel2, tau2, sub2, obj2, r3, rel3, tau3, sub3, obj3;
    if (!i64) {
        const int4 ev = *(const int4*)(edges + (size_t)e0 * 7 + 4 * (g < 6 ? g : 6));
        #define GETF(j) __shfl(((j) & 3) == 0 ? ev.x : ((j) & 3) == 1 ? ev.y : \
                               ((j) & 3) == 2 ? ev.z : ev.w, (j) >> 2, 8)
        r0 = GETF(0);  rel0 = GETF(2);  tau0 = GETF(4);  sub0 = GETF(5);  obj0 = GETF(6);
        r1 = GETF(7);  rel1 = GETF(9);  tau1 = GETF(11); sub1 = GETF(12); obj1 = GETF(13);
        r2 = GETF(14); rel2 = GETF(16); tau2 = GETF(18); sub2 = GETF(19); obj2 = GETF(20);
        r3 = GETF(21); rel3 = GETF(23); tau3 = GETF(25); sub3 = GETF(26); obj3 = GETF(27);
        #undef GETF
    } else {
        const int* E0 = edges + (size_t)(e0    ) * 14;
        const int* E1 = edges + (size_t)(e0 + 1) * 14;
        const int* E2 = edges + (size_t)(e0 + 2) * 14;
        const int* E3 = edges + (size_t)(e0 + 3) * 14;
        r0 = E0[0]; rel0 = E0[4]; tau0 = E0[8]; sub0 = E0[10]; obj0 = E0[12];
        r1 = E1[0]; rel1 = E1[4]; tau1 = E1[8]; sub1 = E1[10]; obj1 = E1[12];
        r2 = E2[0]; rel2 = E2[4]; tau2 = E2[8]; sub2 = E2[10]; obj2 = E2[12];
        r3 = E3[0]; rel3 = E3[4]; tau3 = E3[8]; sub3 = E3[10]; obj3 = E3[12];
    }
    r0 = clampi(r0, 0, N_QUERY - 1); rel0 = clampi(rel0, 0, N_RELV - 1);
    sub0 = clampi(sub0, 0, N_NODE - 1); obj0 = clampi(obj0, 0, N_NODE - 1);
    r1 = clampi(r1, 0, N_QUERY - 1); rel1 = clampi(rel1, 0, N_RELV - 1);
    sub1 = clampi(sub1, 0, N_NODE - 1); obj1 = clampi(obj1, 0, N_NODE - 1);
    r2 = clampi(r2, 0, N_QUERY - 1); rel2 = clampi(rel2, 0, N_RELV - 1);
    sub2 = clampi(sub2, 0, N_NODE - 1); obj2 = clampi(obj2, 0, N_NODE - 1);
    r3 = clampi(r3, 0, N_QUERY - 1); rel3 = clampi(rel3, 0, N_RELV - 1);
    sub3 = clampi(sub3, 0, N_NODE - 1); obj3 = clampi(obj3, 0, N_NODE - 1);

    const int tq0 = lTq[r0];
    const int tq1 = lTq[r1];
    const int tq2 = lTq[r2];
    const int tq3 = lTq[r3];
    if (tau0 < 0) tau0 = tq0;
    if (tau1 < 0) tau1 = tq1;
    if (tau2 < 0) tau2 = tq2;
    if (tau3 < 0) tau3 = tq3;
    const int di0 = clampi(tau0 - tq0 + 365, 0, N_DT - 1);
    const int di1 = clampi(tau1 - tq1 + 365, 0, N_DT - 1);
    const int di2 = clampi(tau2 - tq2 + 365, 0, N_DT - 1);
    const int di3 = clampi(tau3 - tq3 + 365, 0, N_DT - 1);

    // 12 independent global gathers issued back-to-back
    const uint4 xs0 = *(const uint4*)(node_attn + (size_t)sub0 * ATTN_DIM + 8 * g);
    const uint4 xr0 = *(const uint4*)(rel_attn + (size_t)rel0 * ATTN_DIM + 8 * g);
    const uint4 xt0 = *(const uint4*)(dt_attn  + (size_t)di0  * ATTN_DIM + 8 * g);
    const uint4 xs1 = *(const uint4*)(node_attn + (size_t)sub1 * ATTN_DIM + 8 * g);
    const uint4 xr1 = *(const uint4*)(rel_attn + (size_t)rel1 * ATTN_DIM + 8 * g);
    const uint4 xt1 = *(const uint4*)(dt_attn  + (size_t)di1  * ATTN_DIM + 8 * g);
    const uint4 xs2 = *(const uint4*)(node_attn + (size_t)sub2 * ATTN_DIM + 8 * g);
    const uint4 xr2 = *(const uint4*)(rel_attn + (size_t)rel2 * ATTN_DIM + 8 * g);
    const uint4 xt2 = *(const uint4*)(dt_attn  + (size_t)di2  * ATTN_DIM + 8 * g);
    const uint4 xs3 = *(const uint4*)(node_attn + (size_t)sub3 * ATTN_DIM + 8 * g);
    const uint4 xr3 = *(const uint4*)(rel_attn + (size_t)rel3 * ATTN_DIM + 8 * g);
    const uint4 xt3 = *(const uint4*)(dt_attn  + (size_t)di3  * ATTN_DIM + 8 * g);
    // Xqr from LDS
    const uint4 xq0 = *(const uint4*)(lXqr + r0 * 32 + 4 * g);
    const uint4 xq1 = *(const uint4*)(lXqr + r1 * 32 + 4 * g);
    const uint4 xq2 = *(const uint4*)(lXqr + r2 * 32 + 4 * g);
    const uint4 xq3 = *(const uint4*)(lXqr + r3 * 32 + 4 * g);

    __builtin_amdgcn_sched_barrier(0);

    float v0 = dot8(xs0, xr0, xt0, xq0, wA, wB);
    float v1 = dot8(xs1, xr1, xt1, xq1, wA, wB);
    float v2 = dot8(xs2, xr2, xt2, xq2, wA, wB);
    float v3 = dot8(xs3, xr3, xt3, xq3, wA, wB);

    #pragma unroll
    for (int off = 4; off > 0; off >>= 1) {
        v0 += __shfl_xor(v0, off, 8);
        v1 += __shfl_xor(v1, off, 8);
        v2 += __shfl_xor(v2, off, 8);
        v3 += __shfl_xor(v3, off, 8);
    }

    if (g < 4 && e0r + g < N_EDGE) {
        const float vg  = g == 0 ? v0 : (g == 1 ? v1 : (g == 2 ? v2 : v3));
        const int objg  = g == 0 ? obj0 : (g == 1 ? obj1 : (g == 2 ? obj2 : obj3));
        const int subg  = g == 0 ? sub0 : (g == 1 ? sub1 : (g == 2 ? sub2 : sub3));
        const int dig   = g == 0 ? di0  : (g == 1 ? di1  : (g == 2 ? di2  : di3));
        const int relg  = g == 0 ? rel0 : (g == 1 ? rel1 : (g == 2 ? rel2 : rel3));
        const float alpha = 1.f / (1.f + __expf(-(vg + wb)));
        const int pos = atomicAdd(&cnt[objg], 1);
        if (pos < CAP) {
            const uint_t px = (uint_t)subg | ((uint_t)dig << 17) | ((uint_t)(relg & 31) << 27);
            const uint_t py = (uint_t)(relg >> 5) |
                              ((uint_t)__half_as_ushort(__float2half_rn(alpha)) << 16);
            meta[(size_t)pos * N_NODE + objg] = make_int2((int)px, (int)py);
        } else {
            const int ov = atomicAdd(ovfn, 1);
            if (ov < N_EDGE)
                ovfl[ov] = make_int4(subg | (dig << 17), relg | (objg << 9),
                                     __float_as_int(alpha), 0);
        }
    }
}

// ---------------------------------------------------------------------------
// Phase 2: per-node aggregation. QUARTER-wave (16 lanes) per edge with uint4
// gathers; meta double-buffer; XCD-chunked swizzle. msg tables are F16,
// summed with packed v_pk_add_f16 (2 dims/instr) then cvt+FMA into fp32 acc.
// ---------------------------------------------------------------------------
__device__ __forceinline__ void gather3(
    int2 m, int l16,
    const ushort_t* __restrict__ node_msg, const ushort_t* __restrict__ rel_msg,
    const ushort_t* __restrict__ dt_msg,
    uint4& A, uint4& B, uint4& T, float& al)
{
    const int sub = m.x & 0x1FFFF;
    const int di  = ((uint_t)m.x >> 17) & 0x3FF;
    const int rel = (((uint_t)m.x >> 27) & 31) | (((uint_t)m.y & 0xF) << 5);
    al = __half2float(__ushort_as_half((ushort_t)((uint_t)m.y >> 16)));
    A = *(const uint4*)(node_msg + (size_t)sub * 128 + 8 * l16);
    B = *(const uint4*)(rel_msg  + (size_t)rel * 128 + 8 * l16);
    T = *(const uint4*)(dt_msg   + (size_t)di  * 128 + 8 * l16);
}
__device__ __forceinline__ void accum2(uint_t a, uint_t b, uint_t t, float al,
                                       float& lo, float& hi)
{
    const __half2 s = __hadd2(__hadd2(u2h2(a), u2h2(b)), u2h2(t));
    lo += al * __half2float(__low2half(s));
    hi += al * __half2float(__high2half(s));
}
__device__ __forceinline__ void accum8(
    uint4 A, uint4 B, uint4 T, float al,
    float& a0, float& a1, float& a2, float& a3,
    float& a4, float& a5, float& a6, float& a7)
{
    accum2(A.x, B.x, T.x, al, a0, a1);
    accum2(A.y, B.y, T.y, al, a2, a3);
    accum2(A.z, B.z, T.z, al, a4, a5);
    accum2(A.w, B.w, T.w, al, a6, a7);
}

__global__ __launch_bounds__(256) void agg_kernel(
    const int* __restrict__ cnt, const int2* __restrict__ meta,
    const int* __restrict__ ovfn, const int4* __restrict__ ovfl,
    const ushort_t* __restrict__ node_msg, const ushort_t* __restrict__ rel_msg,
    const ushort_t* __restrict__ dt_msg, float* __restrict__ out)
{
    // bijective chunked XCD swizzle (m204 form)
    const int nblk = gridDim.x;                  // 12500
    const int bq = nblk >> 3, br = nblk & 7;
    const int xcd = blockIdx.x & 7, idx = blockIdx.x >> 3;
    const int bswz = (xcd < br ? xcd * (bq + 1)
                               : br * (bq + 1) + (xcd - br) * bq) + idx;

    const int lane = threadIdx.x & 63;
    const int sg   = lane >> 4;                  // 0..3: edge slot in quad
    const int l16  = lane & 15;                  // covers dims 8*l16..+7
    const int n    = bswz * 4 + (threadIdx.x >> 6);

    int m = cnt[n]; if (m > CAP) m = CAP;
    float a0 = 0.f, a1 = 0.f, a2 = 0.f, a3 = 0.f;
    float a4 = 0.f, a5 = 0.f, a6 = 0.f, a7 = 0.f;

    int j = 0;
    if (m >= 8) {
        int2 mA = meta[(size_t)(0 + sg) * N_NODE + n];
        int2 mB = meta[(size_t)(4 + sg) * N_NODE + n];
        for (; j + 7 < m; j += 8) {
            const int2 ca = mA, cb = mB;
            const int ia = (j + 8  + sg < m) ? (j + 8  + sg) : 0;
            const int ib = (j + 12 + sg < m) ? (j + 12 + sg) : 0;
            mA = meta[(size_t)ia * N_NODE + n];
            mB = meta[(size_t)ib * N_NODE + n];
            uint4 Aa, Ba, Ta; float wa;
            uint4 Ab, Bb, Tb; float wbb;
            gather3(ca, l16, node_msg, rel_msg, dt_msg, Aa, Ba, Ta, wa);
            gather3(cb, l16, node_msg, rel_msg, dt_msg, Ab, Bb, Tb, wbb);
            accum8(Aa, Ba, Ta, wa, a0, a1, a2, a3, a4, a5, a6, a7);
            accum8(Ab, Bb, Tb, wbb, a0, a1, a2, a3, a4, a5, a6, a7);
        }
    }
    for (; j < m; j += 4) {                      // masked tail (per sub-group)
        if (j + sg < m) {
            const int2 ma = meta[(size_t)(j + sg) * N_NODE + n];
            uint4 Aa, Ba, Ta; float wa;
            gather3(ma, l16, node_msg, rel_msg, dt_msg, Aa, Ba, Ta, wa);
            accum8(Aa, Ba, Ta, wa, a0, a1, a2, a3, a4, a5, a6, a7);
        }
    }

    // overflow entries (normally none): scan, filter by obj == n, sg 0 only
    int nov = ovfn[0]; if (nov > N_EDGE) nov = N_EDGE;
    for (int i = 0; i < nov; ++i) {
        const int4 mo = ovfl[i];
        const int objo = (int)((uint_t)mo.y >> 9);
        if (objo != n || sg != 0) continue;
        const int subo = mo.x & 0x1FFFF;
        const int dio  = (int)((uint_t)mo.x >> 17);
        const int relo = mo.y & 0x1FF;
        const float alo = __int_as_float(mo.z);
        const uint4 A = *(const uint4*)(node_msg + (size_t)subo * 128 + 8 * l16);
        const uint4 B = *(const uint4*)(rel_msg  + (size_t)relo * 128 + 8 * l16);
        const uint4 T = *(const uint4*)(dt_msg   + (size_t)dio  * 128 + 8 * l16);
        accum8(A, B, T, alo, a0, a1, a2, a3, a4, a5, a6, a7);
    }

    // combine the 4 sub-groups (lane ^16, ^32)
    a0 += __shfl_xor(a0, 16, 64); a0 += __shfl_xor(a0, 32, 64);
    a1 += __shfl_xor(a1, 16, 64); a1 += __shfl_xor(a1, 32, 64);
    a2 += __shfl_xor(a2, 16, 64); a2 += __shfl_xor(a2, 32, 64);
    a3 += __shfl_xor(a3, 16, 64); a3 += __shfl_xor(a3, 32, 64);
    a4 += __shfl_xor(a4, 16, 64); a4 += __shfl_xor(a4, 32, 64);
    a5 += __shfl_xor(a5, 16, 64); a5 += __shfl_xor(a5, 32, 64);
    a6 += __shfl_xor(a6, 16, 64); a6 += __shfl_xor(a6, 32, 64);
    a7 += __shfl_xor(a7, 16, 64); a7 += __shfl_xor(a7, 32, 64);

    if (sg == 0) {
        float4 o0; o0.x = a0; o0.y = a1; o0.z = a2; o0.w = a3;
        float4 o1; o1.x = a4; o1.y = a5; o1.z = a6; o1.w = a7;
        *(float4*)(out + (size_t)n * OUT_DIM + 8 * l16)     = o0;
        *(float4*)(out + (size_t)n * OUT_DIM + 8 * l16 + 4) = o1;
    }
}

// ---------------------------------------------------------------------------
// Fallback: single-pass atomic edge kernel (small-workspace path).
// msg tables are F16 (must match fused_pre's output format).
// ---------------------------------------------------------------------------
__device__ __forceinline__ void parse_edge(const int* __restrict__ edges, int e,
                                           int i64, int& r, int& rel, int& tau,
                                           int& sub, int& obj) {
    if (i64) {
        const int* E = edges + (size_t)e * 14;
        r = E[0]; rel = E[4]; tau = E[8]; sub = E[10]; obj = E[12];
    } else {
        const int* E = edges + (size_t)e * 7;
        r = E[0]; rel = E[2]; tau = E[4]; sub = E[5]; obj = E[6];
    }
    r   = clampi(r,   0, N_QUERY - 1);
    rel = clampi(rel, 0, N_RELV - 1);
    sub = clampi(sub, 0, N_NODE - 1);
    obj = clampi(obj, 0, N_NODE - 1);
}

__global__ __launch_bounds__(256) void edge_atomic_kernel(
    const int* __restrict__ edges, const int* __restrict__ q_tau,
    const ushort_t* __restrict__ node_attn, const ushort_t* __restrict__ node_msg,
    const ushort_t* __restrict__ rel_attn,  const ushort_t* __restrict__ rel_msg,
    const ushort_t* __restrict__ dt_attn,   const ushort_t* __restrict__ dt_msg,
    const ushort_t* __restrict__ Xqr,
    const float* __restrict__ w_alpha_W, const float* __restrict__ w_alpha_b,
    const int* __restrict__ flag, float* __restrict__ out)
{
    const int lane = threadIdx.x & 63;
    const int e    = blockIdx.x * 4 + (threadIdx.x >> 6);
    const int i64  = flag[0];

    int r, rel, tau, sub, obj;
    parse_edge(edges, e, i64, r, rel, tau, sub, obj);
    const int tq = q_tau[i64 ? 2 * r : r];
    if (tau < 0) tau = tq;
    const int di = clampi(tau - tq + 365, 0, N_DT - 1);

    const float xs = bu2f(node_attn[(size_t)sub * ATTN_DIM + lane]);
    const float xr = bu2f(rel_attn[(size_t)rel * ATTN_DIM + lane]);
    const float xt = bu2f(dt_attn[(size_t)di  * ATTN_DIM + lane]);
    const float xq = bu2f(Xqr[(size_t)r * ATTN_DIM + lane]);

    float v = fmaxf(xs + xr + xq + xt, 0.f) * w_alpha_W[lane];
    #pragma unroll
    for (int off = 32; off > 0; off >>= 1)
        v += __shfl_down(v, off, 64);
    v = __shfl(v, 0, 64);
    const float alpha = 1.f / (1.f + __expf(-(v + w_alpha_b[0])));

    const uint_t am = *(const uint_t*)(node_msg + (size_t)sub * 128 + 2 * lane);
    const uint_t bm = *(const uint_t*)(rel_msg  + (size_t)rel * 128 + 2 * lane);
    const uint_t tm = *(const uint_t*)(dt_msg   + (size_t)di  * 128 + 2 * lane);
    const __half2 s = __hadd2(__hadd2(u2h2(am), u2h2(bm)), u2h2(tm));
    const float mx = __half2float(__low2half(s));
    const float my = __half2float(__high2half(s));

    float* dst = out + (size_t)obj * OUT_DIM;
    atomicAdd(dst + 2 * lane,     alpha * mx);
    atomicAdd(dst + 2 * lane + 1, alpha * my);
}

// ===========================================================================
extern "C" void kernel_launch(void* const* d_in, const int* in_sizes, int n_in,
                              void* d_out, int out_size, void* d_ws, size_t ws_size,
                              hipStream_t stream)
{
    const int*   q_rel  = (const int*)d_in[1];
    const int*   q_tau  = (const int*)d_in[2];
    const float* hidden = (const float*)d_in[3];
    const int*   edges  = (const int*)d_in[4];
    const float* rela   = (const float*)d_in[7];
    const float* Ws     = (const float*)d_in[8];
    const float* Wr     = (const float*)d_in[9];
    const float* WqrW   = (const float*)d_in[10];
    const float* Wqrb   = (const float*)d_in[11];
    const float* Wtau   = (const float*)d_in[12];
    const float* waW    = (const float*)d_in[13];
    const float* wab    = (const float*)d_in[14];
    const float* Wh     = (const float*)d_in[15];
    const float* wt1    = (const float*)d_in[16];
    const float* bt1    = (const float*)d_in[17];
    const float* wt2    = (const float*)d_in[18];
    const float* bt2    = (const float*)d_in[19];
    float* out = (float*)d_out;

    // --- workspace carve (256-B aligned chunks) ---
    char* p = (char*)d_ws;
    size_t off = 0;
    auto carve = [&](size_t bytes) {
        char* q = p + off;
        off = (off + bytes + 255) & ~(size_t)255;
        return q;
    };
    int*      flag      = (int*)     carve(64);
    int*      cnt       = (int*)     carve((size_t)N_NODE * 4);
    int*      ovfn      = (int*)     carve(64);
    ushort_t* XqrB      = (ushort_t*)carve((size_t)N_QUERY * ATTN_DIM * 2);
    ushort_t* rel_attn  = (ushort_t*)carve((size_t)N_RELV * ATTN_DIM * 2);
    ushort_t* rel_msg   = (ushort_t*)carve((size_t)N_RELV * OUT_DIM * 2);
    ushort_t* dt_attn   = (ushort_t*)carve((size_t)N_DT * ATTN_DIM * 2);
    ushort_t* dt_msg    = (ushort_t*)carve((size_t)N_DT * OUT_DIM * 2);
    ushort_t* node_attn = (ushort_t*)carve((size_t)N_NODE * ATTN_DIM * 2);
    ushort_t* node_msg  = (ushort_t*)carve((size_t)N_NODE * OUT_DIM * 2);
    int2*     meta      = (int2*)    carve((size_t)N_NODE * CAP * 8);
    int4*     ovfl      = (int4*)    carve((size_t)N_EDGE * 16);
    const size_t need_full = off;

    fused_pre<<<NB_TOT, 256, 0, stream>>>(
        hidden, Ws, Wh, rela, Wr, Wtau, wt1, bt1, wt2, bt2,
        q_rel, WqrW, Wqrb, edges,
        node_attn, node_msg, rel_attn, rel_msg, dt_attn, dt_msg, XqrB,
        flag, cnt, ovfn);

    if (ws_size >= need_full) {
        alpha_scatter<<<(N_EDGE + 127) / 128, 256, 0, stream>>>(
            edges, q_tau, node_attn, rel_attn, dt_attn, XqrB,
            waW, wab, flag, cnt, meta, ovfn, ovfl);
        agg_kernel<<<N_NODE / 4, 256, 0, stream>>>(cnt, meta, ovfn, ovfl,
                                                   node_msg, rel_msg, dt_msg, out);
    } else {
        (void)hipMemsetAsync(out, 0, (size_t)out_size * sizeof(float), stream);
        edge_atomic_kernel<<<N_EDGE / 4, 256, 0, stream>>>(edges, q_tau,
                                                           node_attn, node_msg,
                                                           rel_attn, rel_msg,
                                                           dt_attn, dt_msg, XqrB,
                                                           waW, wab, flag, out);
    }
}